// Round 1
// baseline (194.545 us; speedup 1.0000x reference)
//
#include <hip/hip_runtime.h>
#include <hip/hip_bf16.h>

// Problem constants
#define NG   8
#define ND   16
#define NL   1024
#define NB   16
#define NE   8
#define NOUT 64
#define NKS  3
#define NK   4
#define NLP  1022   // L - KS + 1

// Output layout (flat concat of reference return tuple)
#define OUT_LOSS  (NB*NG*NOUT*NLP)   // 8372224
#define OUT_GATES (OUT_LOSS + 1)     // 8372225

// ---------------------------------------------------------------------------
// Kernel 1: gating (softmax -> top4 -> normalized gates), gates_out, loss.
// One block, 128 threads: thread t -> (g = t>>4, b = t&15).
// ---------------------------------------------------------------------------
__global__ __launch_bounds__(128) void gate_kernel(
    const float* __restrict__ x, const float* __restrict__ wg,
    float* __restrict__ out, float* __restrict__ ws_gates)
{
    const int t = threadIdx.x;          // 0..127
    const int g = t >> 4, b = t & 15;

    // gate_in = x[b, g*16+d, 1018+tt]  (L-6 .. L-2), reshaped (d*5+tt)
    float gi[80];
    const float* xrow = x + (size_t)(b * 128 + g * 16) * 1024 + (1024 - 6);
    #pragma unroll
    for (int d = 0; d < 16; ++d) {
        #pragma unroll
        for (int tt = 0; tt < 5; ++tt) gi[d * 5 + tt] = xrow[d * 1024 + tt];
    }

    // logits = gate_in @ wg[g]   (80 x 8)
    float lg[8];
    #pragma unroll
    for (int e = 0; e < 8; ++e) lg[e] = 0.f;
    const float* wgg = wg + g * 80 * 8;
    #pragma unroll
    for (int j = 0; j < 80; ++j) {
        const float v = gi[j];
        #pragma unroll
        for (int e = 0; e < 8; ++e) lg[e] = fmaf(v, wgg[j * 8 + e], lg[e]);
    }

    // softmax (8)
    float mx = lg[0];
    #pragma unroll
    for (int e = 1; e < 8; ++e) mx = fmaxf(mx, lg[e]);
    float s = 0.f;
    #pragma unroll
    for (int e = 0; e < 8; ++e) { lg[e] = expf(lg[e] - mx); s += lg[e]; }
    const float invsm = 1.f / s;
    #pragma unroll
    for (int e = 0; e < 8; ++e) lg[e] *= invsm;

    // top-4 (strict >, first-index tie-break == jax top_k order), static indexing
    int used = 0;
    float tv[4]; int ti[4];
    #pragma unroll
    for (int k = 0; k < 4; ++k) {
        float bv = -1.f; int be = 0;
        #pragma unroll
        for (int e = 0; e < 8; ++e) {
            if (!((used >> e) & 1) && lg[e] > bv) { bv = lg[e]; be = e; }
        }
        tv[k] = bv; ti[k] = be; used |= (1 << be);
    }
    const float s4 = tv[0] + tv[1] + tv[2] + tv[3];
    const float invs = 1.f / (s4 + 1e-6f);

    float gates[8];
    #pragma unroll
    for (int e = 0; e < 8; ++e) {
        float v = 0.f;
        #pragma unroll
        for (int k = 0; k < 4; ++k) if (ti[k] == e) v = tv[k] * invs;
        gates[e] = v;
        ws_gates[t * 8 + e] = v;
        // gates_out[b, e, g]
        out[OUT_GATES + (b * 8 + e) * 8 + g] = v;
    }

    // ---- loss: per group, cv^2(importance) + cv^2(load), ddof=1 over E=8 ----
    __shared__ float glds[128][8];
    #pragma unroll
    for (int e = 0; e < 8; ++e) glds[t][e] = gates[e];
    __syncthreads();

    __shared__ float impa[64], loda[64];
    if (t < 64) {
        const int gg = t >> 3, e = t & 7;
        float si = 0.f, sl = 0.f;
        for (int bb = 0; bb < 16; ++bb) {
            const float v = glds[gg * 16 + bb][e];
            si += v;
            sl += (v > 0.f) ? 1.f : 0.f;
        }
        impa[t] = si; loda[t] = sl;
    }
    __syncthreads();

    __shared__ float lossg[8];
    if (t < 8) {
        float m1 = 0.f, m2 = 0.f;
        #pragma unroll
        for (int e = 0; e < 8; ++e) { m1 += impa[t * 8 + e]; m2 += loda[t * 8 + e]; }
        m1 *= 0.125f; m2 *= 0.125f;
        float v1 = 0.f, v2 = 0.f;
        #pragma unroll
        for (int e = 0; e < 8; ++e) {
            const float d1 = impa[t * 8 + e] - m1, d2 = loda[t * 8 + e] - m2;
            v1 += d1 * d1; v2 += d2 * d2;
        }
        v1 *= (1.f / 7.f); v2 *= (1.f / 7.f);
        lossg[t] = v1 / (m1 * m1 + 1e-10f) + v2 / (m2 * m2 + 1e-10f);
    }
    __syncthreads();
    if (t == 0) {
        float tot = 0.f;
        #pragma unroll
        for (int gg = 0; gg < 8; ++gg) tot += lossg[gg];
        out[OUT_LOSS] = 0.01f * tot;
    }
}

// ---------------------------------------------------------------------------
// Kernel 2: fold gates into conv2 weights: W_eff[g,b,o,i] = sum_e g_e * c2w[g,o*8+e,i]
// 128 blocks (one per (g,b)), 64 threads (i).
// ---------------------------------------------------------------------------
__global__ __launch_bounds__(64) void weff_kernel(
    const float* __restrict__ gates, const float* __restrict__ c2w,
    const float* __restrict__ c2b,
    float* __restrict__ weff, float* __restrict__ beff)
{
    const int gb = blockIdx.x;           // 0..127
    const int g  = gb >> 4;
    const int i  = threadIdx.x;          // 0..63

    float gt[8];
    #pragma unroll
    for (int e = 0; e < 8; ++e) gt[e] = gates[gb * 8 + e];

    const float* w2g = c2w + (size_t)g * 512 * 64;
    float* wout = weff + (size_t)gb * 4096;
    for (int o = 0; o < 64; ++o) {
        float acc = 0.f;
        #pragma unroll
        for (int e = 0; e < 8; ++e)
            acc = fmaf(gt[e], w2g[(o * 8 + e) * 64 + i], acc);
        wout[o * 64 + i] = acc;
    }
    // b_eff[o=i] = sum_e g_e * c2b[g, i*8+e]
    float acc = 0.f;
    const float* b2g = c2b + g * 512;
    #pragma unroll
    for (int e = 0; e < 8; ++e) acc = fmaf(gt[e], b2g[i * 8 + e], acc);
    beff[gb * 64 + i] = acc;
}

// ---------------------------------------------------------------------------
// Kernel 3: fused conv1 -> tanh -> (gate-folded 64x64) -> output.
// Grid: 512 blocks = (g, b, ltile[4 x 256]); 256 threads, one column each.
// All weight reads are wave-uniform (threadIdx-free) -> scalar s_loads.
// Both o-loops fully unrolled so h[]/xv[] stay in registers (no scratch).
// ---------------------------------------------------------------------------
__global__ __launch_bounds__(256) void main_kernel(
    const float* __restrict__ x, const float* __restrict__ w1,
    const float* __restrict__ b1, const float* __restrict__ weff,
    const float* __restrict__ beff, float* __restrict__ out)
{
    const int bid  = blockIdx.x;
    const int tile = bid & 3;
    const int b    = (bid >> 2) & 15;
    const int g    = bid >> 6;
    const int l    = tile * 256 + threadIdx.x;
    if (l >= NLP) return;
    const int gb = g * 16 + b;

    // load 16 channels x 3 taps
    const float* xbase = x + (size_t)(b * 128 + g * 16) * 1024 + l;
    float xv[16][3];
    #pragma unroll
    for (int i = 0; i < 16; ++i) {
        xv[i][0] = xbase[i * 1024 + 0];
        xv[i][1] = xbase[i * 1024 + 1];
        xv[i][2] = xbase[i * 1024 + 2];
    }

    // conv1 + tanh
    float h[64];
    const float* w1g = w1 + g * 64 * 48;
    const float* b1g = b1 + g * 64;
    #pragma unroll
    for (int o = 0; o < 64; ++o) {
        float acc = b1g[o];
        const float* wr = w1g + o * 48;
        #pragma unroll
        for (int i = 0; i < 16; ++i) {
            acc = fmaf(wr[i * 3 + 0], xv[i][0], acc);
            acc = fmaf(wr[i * 3 + 1], xv[i][1], acc);
            acc = fmaf(wr[i * 3 + 2], xv[i][2], acc);
        }
        h[o] = tanhf(acc);
    }

    // gate-folded conv2 (64x64 matvec per column) + store
    const float* wef = weff + (size_t)gb * 4096;
    const float* bef = beff + gb * 64;
    float* obase = out + (size_t)((b * 8 + g) * 64) * NLP + l;
    #pragma unroll
    for (int o = 0; o < 64; ++o) {
        float acc = bef[o];
        const float* wr = wef + o * 64;
        #pragma unroll
        for (int i = 0; i < 64; ++i) acc = fmaf(wr[i], h[i], acc);
        obase[(size_t)o * NLP] = acc;
    }
}

// ---------------------------------------------------------------------------
extern "C" void kernel_launch(void* const* d_in, const int* in_sizes, int n_in,
                              void* d_out, int out_size, void* d_ws, size_t ws_size,
                              hipStream_t stream) {
    const float* x   = (const float*)d_in[0];
    const float* wg  = (const float*)d_in[1];
    const float* c1w = (const float*)d_in[2];
    const float* c1b = (const float*)d_in[3];
    const float* c2w = (const float*)d_in[4];
    const float* c2b = (const float*)d_in[5];
    float* out = (float*)d_out;

    float* ws       = (float*)d_ws;
    float* ws_gates = ws;                  // 128*8      = 1024 floats
    float* beff     = ws + 1024;           // 128*64     = 8192 floats
    float* weff     = ws + 1024 + 8192;    // 128*64*64  = 524288 floats
    // total ws: ~2.1 MB

    gate_kernel<<<1, 128, 0, stream>>>(x, wg, out, ws_gates);
    weff_kernel<<<128, 64, 0, stream>>>(ws_gates, c2w, c2b, weff, beff);
    main_kernel<<<512, 256, 0, stream>>>(x, c1w, c1b, weff, beff, out);
}